// Round 13
// baseline (1711.407 us; speedup 1.0000x reference)
//
#include <hip/hip_runtime.h>
#include <hip/hip_bf16.h>

#define B_ROWS 8192
#define D_DIM  2048
#define C_DIM  1000
#define C_PAD  1024

#define EPS32   1.1920928955078125e-07f
// GAMMA = 1/exp(100) ~ 3.7e-44 => loss == mean(h3) exactly in fp32 (round 5).
// Round 15: rownorm deleted via row-sum linearity (rowsum = z.wsum + bsum).
// Round 17: wsum block-starvation fixed (125 coalesced blocks, ~4us).
// Round 18 (this): fuse_z + gemm merged into ONE producer/consumer kernel.
// Rationale: every kernel is individually plateaued (fuse_z ~55us across 5
// variants, HBM-bound, MFMA idle; gemm ~56us, L2-latency-bound, HBM 15%) and
// they use disjoint resources but run serially. mega = 64 groups x [128
// z-producer blocks (row panel) + 16 gemm blocks (x-tile)]; consumers spin on
// a per-panel device-scope flag. No-deadlock: 1024 gemm blocks cap at ~170 CUs
// (6/CU LDS) -> >=85 CUs always free for producers. Coherence: producers
// __threadfence (wbl2) + release atomicAdd; consumer z-lines can't be stale in
// its L2 (fresh kernel, row-private cachelines, first touch after flag) so a
// relaxed spin + __syncthreads suffices (no L2-invalidating acquire). Flags
// re-zeroed every iteration by prep (graph-replay safe).

typedef __attribute__((ext_vector_type(8))) short short8;   // 8 bf16 = 4 VGPRs
typedef __attribute__((ext_vector_type(4))) float f32x4;    // MFMA accumulator

#define GLOAD_LDS16(gptr, lptr) \
  __builtin_amdgcn_global_load_lds((const __attribute__((address_space(1))) void*)(gptr), \
                                   (__attribute__((address_space(3))) void*)(lptr), 16, 0, 0)

__device__ inline unsigned short f2bf(float x) {
  union { __hip_bfloat16 b; unsigned short u; } cv;
  cv.b = __float2bfloat16(x);
  return cv.u;
}

__device__ inline float bf2f(unsigned short u) {
  union { unsigned int i; float f; } c;
  c.i = (unsigned int)u << 16;
  return c.f;
}

__device__ inline float wave_red(float v) {
#pragma unroll
  for (int off = 32; off > 0; off >>= 1) v += __shfl_down(v, off, 64);
  return v;
}

// ---- prep:
//   blocks [0,1024):     cast cls_w -> bf16 padded [1024][2048] (1 row/block).
//   blocks [1024,1149):  partial[g][c] = sum of cls_w rows [8g,8g+8) coalesced.
//   block 1149:          bsum = sum(cls_b); zero the 64 panel flags.
__global__ __launch_bounds__(256) void prep(const float* __restrict__ cls_w,
                                            __hip_bfloat16* __restrict__ clsw_bf,
                                            const float* __restrict__ cls_b,
                                            float* __restrict__ partial,
                                            float* __restrict__ bsum,
                                            unsigned int* __restrict__ flags) {
  int bid = blockIdx.x, tid = threadIdx.x;
  if (bid < 1024) {
    int j = (bid * 256 + tid) * 8;   // elem idx in [1024][2048]
    int row = j >> 11;
    int col = j & 2047;
    union { unsigned short u[8]; uint4 v; } pk;
    if (row < C_DIM) {
      const float* src = cls_w + (size_t)row * D_DIM + col;
#pragma unroll
      for (int i2 = 0; i2 < 8; ++i2) pk.u[i2] = f2bf(src[i2]);
    } else {
#pragma unroll
      for (int i2 = 0; i2 < 8; ++i2) pk.u[i2] = 0;
    }
    *(uint4*)((unsigned short*)clsw_bf + j) = pk.v;
  } else if (bid < 1149) {
    int g = bid - 1024;
    const float* base = cls_w + (size_t)g * 8 * D_DIM + tid * 8;
    float4 sA = {0.f, 0.f, 0.f, 0.f}, sB = {0.f, 0.f, 0.f, 0.f};
#pragma unroll
    for (int r = 0; r < 8; ++r) {
      float4 a = *(const float4*)(base + (size_t)r * D_DIM);
      float4 b = *(const float4*)(base + (size_t)r * D_DIM + 4);
      sA.x += a.x; sA.y += a.y; sA.z += a.z; sA.w += a.w;
      sB.x += b.x; sB.y += b.y; sB.z += b.z; sB.w += b.w;
    }
    float* dst = partial + (size_t)g * D_DIM + tid * 8;
    *(float4*)dst = sA;
    *(float4*)(dst + 4) = sB;
  } else {
    if (tid < 64) flags[tid] = 0;     // re-zero panel flags EVERY iteration
    float s = 0.f;
    int i0 = tid * 4;
    if (i0 < C_DIM)                   // 250 threads x 4 = 1000
      s = cls_b[i0] + cls_b[i0 + 1] + cls_b[i0 + 2] + cls_b[i0 + 3];
    s = wave_red(s);
    __shared__ float sm[4];
    if ((tid & 63) == 0) sm[tid >> 6] = s;
    __syncthreads();
    if (tid == 0) bsum[0] = sm[0] + sm[1] + sm[2] + sm[3];
  }
}

// ---- wsum_fin: wsum[c] = sum_{g<125} partial[g][c]. 1MB L2-resident input.
__global__ __launch_bounds__(256) void wsum_fin(const float* __restrict__ partial,
                                                float* __restrict__ wsum) {
  int c = blockIdx.x * 256 + threadIdx.x;
  float s = 0.f;
  for (int g = 0; g < 125; ++g) s += partial[(size_t)g * D_DIM + c];
  wsum[c] = s;
}

// ---- mega: 64 groups x 144 blocks.
//   r in [0,128):  PRODUCER — z row = g*128+r: pack bf16(feature+eps), rowsum,
//                  then threadfence + release flag increment.
//   r in [128,144): CONSUMER — gemm x-tile g, y-tile r-128 (proven r13 128x64
//                  single-buffer body + fused normalize/clamp/log epilogue);
//                  spins (relaxed) until flags[g]==128.
__global__ __launch_bounds__(256) void mega(const float4* __restrict__ f4,
                                            const float4* __restrict__ e4,
                                            uint4* __restrict__ z4,
                                            const __hip_bfloat16* __restrict__ A,
                                            const __hip_bfloat16* __restrict__ Bt,
                                            const float* __restrict__ cls_b,
                                            const float* __restrict__ wsum,
                                            const float* __restrict__ bsum,
                                            float* __restrict__ rowsum,
                                            const int* __restrict__ target,
                                            float* __restrict__ out,
                                            float* __restrict__ rowloss,
                                            unsigned int* __restrict__ flags) {
  __shared__ __align__(16) __hip_bfloat16 sA[128 * 64];   // 16 KB (gemm path)
  __shared__ __align__(16) __hip_bfloat16 sB[64 * 64];    //  8 KB (gemm path)
  __shared__ float sm[4];                                 // (producer path)

  const int bid = blockIdx.x, tid = threadIdx.x;
  const int g = bid / 144;
  const int r = bid - g * 144;

  if (r < 128) {
    // ---------------- producer: one z row ----------------
    const int row = g * 128 + r;
    int t = row * 256 + tid;
    int i0 = t * 2;
    float4 f0 = f4[i0], f1 = f4[i0 + 1];
    float4 e0 = e4[i0], e1 = e4[i0 + 1];
    float4 w0 = *(const float4*)(wsum + tid * 8);
    float4 w1 = *(const float4*)(wsum + tid * 8 + 4);
    union { unsigned short u[8]; uint4 v; } pz;
    pz.u[0] = f2bf(f0.x + e0.x);
    pz.u[1] = f2bf(f0.y + e0.y);
    pz.u[2] = f2bf(f0.z + e0.z);
    pz.u[3] = f2bf(f0.w + e0.w);
    pz.u[4] = f2bf(f1.x + e1.x);
    pz.u[5] = f2bf(f1.y + e1.y);
    pz.u[6] = f2bf(f1.z + e1.z);
    pz.u[7] = f2bf(f1.w + e1.w);
    z4[t] = pz.v;

    float d = bf2f(pz.u[0]) * w0.x + bf2f(pz.u[1]) * w0.y +
              bf2f(pz.u[2]) * w0.z + bf2f(pz.u[3]) * w0.w +
              bf2f(pz.u[4]) * w1.x + bf2f(pz.u[5]) * w1.y +
              bf2f(pz.u[6]) * w1.z + bf2f(pz.u[7]) * w1.w;
    d = wave_red(d);
    if ((tid & 63) == 0) sm[tid >> 6] = d;
    __syncthreads();
    if (tid == 0) rowsum[row] = sm[0] + sm[1] + sm[2] + sm[3] + bsum[0];
    __threadfence();               // push z + rowsum to agent visibility (wbl2)
    __syncthreads();               // all threads' stores/fences complete
    if (tid == 0)
      __hip_atomic_fetch_add(&flags[g], 1u, __ATOMIC_RELEASE, __HIP_MEMORY_SCOPE_AGENT);
    return;
  }

  // ---------------- consumer: gemm tile (m0 = g*128, n0 = (r-128)*64) -------
  if (tid == 0) {
    while (__hip_atomic_load(&flags[g], __ATOMIC_RELAXED, __HIP_MEMORY_SCOPE_AGENT) < 128u)
      __builtin_amdgcn_s_sleep(2);
  }
  __syncthreads();   // gates all z reads behind the observed flag (no stale
                     // copy can exist in this L2: fresh kernel, row-private
                     // lines, first touch after flag)

  const int m0 = g * 128;
  const int n0 = (r - 128) * 64;
  const int w = tid >> 6, lane = tid & 63;
  const int wm = (w & 1) * 64, wn = (w >> 1) * 32;
  const int l15 = lane & 15, quad = lane >> 4;

  f32x4 acc[4][2] = {};

  for (int k0 = 0; k0 < D_DIM; k0 += 64) {
#pragma unroll
    for (int i = 0; i < 4; ++i) {
      int j = i * 256 + tid;          // A: 1024 chunks of 16B (128 rows x 8)
      int row = j >> 3;
      int cc = (j & 7) ^ (row & 7);   // XOR-swizzle (involution)
      GLOAD_LDS16(A + (size_t)(m0 + row) * D_DIM + k0 + cc * 8, &sA[j * 8]);
    }
#pragma unroll
    for (int i = 0; i < 2; ++i) {
      int j = i * 256 + tid;          // B: 512 chunks (64 rows x 8)
      int row = j >> 3;
      int cc = (j & 7) ^ (row & 7);
      GLOAD_LDS16(Bt + (size_t)(n0 + row) * D_DIM + k0 + cc * 8, &sB[j * 8]);
    }
    __syncthreads();
#pragma unroll
    for (int kk = 0; kk < 64; kk += 32) {
      const int ccr = (kk >> 3) + quad;   // which 8-elem chunk along K
      short8 af[4], bfr[2];
#pragma unroll
      for (int i = 0; i < 4; ++i) {
        int rr = wm + i * 16 + l15;
        af[i] = *(const short8*)&sA[(rr * 8 + (ccr ^ (rr & 7))) * 8];
      }
#pragma unroll
      for (int jn = 0; jn < 2; ++jn) {
        int rr = wn + jn * 16 + l15;
        bfr[jn] = *(const short8*)&sB[(rr * 8 + (ccr ^ (rr & 7))) * 8];
      }
#pragma unroll
      for (int i = 0; i < 4; ++i)
#pragma unroll
        for (int jn = 0; jn < 2; ++jn)
          acc[i][jn] = __builtin_amdgcn_mfma_f32_16x16x32_bf16(af[i], bfr[jn], acc[i][jn], 0, 0, 0);
    }
    __syncthreads();
  }

  // fused epilogue: C/D layout col=lane&15, row=quad*4+reg (m89-verified)
  float bias[2]; int bcol[2];
#pragma unroll
  for (int jn = 0; jn < 2; ++jn) {
    bcol[jn] = n0 + wn + jn * 16 + l15;
    bias[jn] = (bcol[jn] < C_DIM) ? cls_b[bcol[jn]] : 0.f;
  }
  const int rowb = m0 + wm + quad * 4;
  float rinv[16]; int tgt[16];
#pragma unroll
  for (int i = 0; i < 4; ++i)
#pragma unroll
    for (int rr = 0; rr < 4; ++rr) {
      rinv[i * 4 + rr] = rowsum[rowb + i * 16 + rr];
      tgt[i * 4 + rr]  = target[rowb + i * 16 + rr];
    }
#pragma unroll
  for (int k = 0; k < 16; ++k) rinv[k] = 1.0f / rinv[k];

#pragma unroll
  for (int i = 0; i < 4; ++i) {
#pragma unroll
    for (int rr = 0; rr < 4; ++rr) {
      int row = rowb + i * 16 + rr;
      float inv = rinv[i * 4 + rr];
      int tg = tgt[i * 4 + rr];
      float* orow = out + (size_t)row * C_DIM;
#pragma unroll
      for (int jn = 0; jn < 2; ++jn) {
        int col = bcol[jn];
        if (col < C_DIM) {
          float p = (acc[i][jn][rr] + bias[jn]) * inv;
          p = fminf(fmaxf(p, EPS32), 1.0f - EPS32);
          float lg = __logf(p);
          orow[col] = lg;
          if (col == tg) rowloss[row] = -lg;
        }
      }
    }
  }
}

// ---- finalize: loss = mean(rowloss). One 1024-thread block, ILP-8, plain store.
__global__ __launch_bounds__(1024) void finalize(const float* __restrict__ rowloss,
                                                 float* __restrict__ out_loss) {
  int tid = threadIdx.x;
  float a[8];
#pragma unroll
  for (int j = 0; j < 8; ++j) a[j] = rowloss[tid + j * 1024];
  float s = 0.f;
#pragma unroll
  for (int j = 0; j < 8; ++j) s += a[j];
  s = wave_red(s);
  __shared__ float sm[16];
  if ((tid & 63) == 0) sm[tid >> 6] = s;
  __syncthreads();
  if (tid == 0) {
    float t = 0.f;
#pragma unroll
    for (int k = 0; k < 16; ++k) t += sm[k];
    out_loss[0] = t * (1.0f / B_ROWS);
  }
}

extern "C" void kernel_launch(void* const* d_in, const int* in_sizes, int n_in,
                              void* d_out, int out_size, void* d_ws, size_t ws_size,
                              hipStream_t stream) {
  const float* feature = (const float*)d_in[0];
  const float* cls_w   = (const float*)d_in[3];
  const float* cls_b   = (const float*)d_in[4];
  const float* eps     = (const float*)d_in[5];
  const int*   target  = (const int*)d_in[6];
  float* out = (float*)d_out;
  float* out_loss = out + (size_t)B_ROWS * C_DIM;

  char* ws = (char*)d_ws;
  __hip_bfloat16* z_bf    = (__hip_bfloat16*)ws;                   // 33554432 B
  __hip_bfloat16* clsw_bf = (__hip_bfloat16*)(ws + 33554432);      //  4194304 B
  float*          rowloss = (float*)(ws + 37748736);               //    32768 B
  float*          rowsum  = (float*)(ws + 37781504);               //    32768 B
  float*          wsum    = (float*)(ws + 37814272);               //     8192 B
  float*          bsum    = (float*)(ws + 37822464);               //      256 B
  float*          partial = (float*)(ws + 37822720);               //  1024000 B
  unsigned int*   flags   = (unsigned int*)(ws + 38846720);        //      256 B

  prep<<<dim3(1024 + 125 + 1), 256, 0, stream>>>(cls_w, clsw_bf, cls_b, partial, bsum, flags);
  wsum_fin<<<dim3(8), 256, 0, stream>>>(partial, wsum);
  mega<<<dim3(64 * 144), 256, 0, stream>>>((const float4*)feature, (const float4*)eps,
                                           (uint4*)z_bf, z_bf, clsw_bf, cls_b,
                                           wsum, bsum, rowsum, target, out, rowloss, flags);
  finalize<<<dim3(1), 1024, 0, stream>>>(rowloss, out_loss);
}

// Round 14
// 236.172 us; speedup vs baseline: 7.2464x; 7.2464x over previous
//
#include <hip/hip_runtime.h>
#include <hip/hip_bf16.h>

#define B_ROWS 8192
#define D_DIM  2048
#define C_DIM  1000
#define C_PAD  1024

#define EPS32   1.1920928955078125e-07f
// GAMMA = 1/exp(100) ~ 3.7e-44. GAMMA*rex ~ 1e-40 << ulp(h3~6.9) ~ 4.8e-7,
// so loss == mean(h3) exactly in fp32. rex pipeline deleted (round 5).
// Round 18 (producer/consumer mega) REVERTED: 1593us, 7x regression — consumer
// spin at agent scope + per-row threadfence serialized the machine. Inter-block
// sync inside a grid is a dead end here.
// Round 19 (this): best-of-measured recombination, never run together before:
//   - fuse_z: round-0 variant (best single measurement 54.6us; 5 variants all
//     54-56 => plateau).
//   - gemm_bt: r13 128x64 single-buffer plain-epilogue (fastest gemm variant,
//     ~46-50us; dbuf null x2, fused epilogue +3-6us).
//   - rownorm: 4 rows/wave ILP-16 (r12 fix, ~45us).
//   - finalize: 1024-thread ILP-8.
// Ledger: kernel-sum ~150us, residual ~80us tracks launch count (~15-20/launch),
// not addressable from kernel source (r18 proved the alternative costs 7x).

typedef __attribute__((ext_vector_type(8))) short short8;   // 8 bf16 = 4 VGPRs
typedef __attribute__((ext_vector_type(4))) float f32x4;    // MFMA accumulator

#define GLOAD_LDS16(gptr, lptr) \
  __builtin_amdgcn_global_load_lds((const __attribute__((address_space(1))) void*)(gptr), \
                                   (__attribute__((address_space(3))) void*)(lptr), 16, 0, 0)

__device__ inline unsigned short f2bf(float x) {
  union { __hip_bfloat16 b; unsigned short u; } cv;
  cv.b = __float2bfloat16(x);
  return cv.u;
}

__device__ inline float wave_red(float v) {
#pragma unroll
  for (int off = 32; off > 0; off >>= 1) v += __shfl_down(v, off, 64);
  return v;
}

// ---- B+P merged (round-0 proven, 54.6us):
//   blocks [0,16384):      z_bf[i] = bf16(feature[i] + eps[i]), one float4-pair
//                          per thread (max TLP: ~32 waves/CU, 2 loads each).
//   blocks [16384,17408):  cast cls_w [1000,2048] -> bf16 padded [1024,2048].
__global__ __launch_bounds__(256) void fuse_z(const float4* __restrict__ f4,
                                              const float4* __restrict__ e4,
                                              uint2* __restrict__ z,
                                              const float* __restrict__ cls_w,
                                              __hip_bfloat16* __restrict__ clsw_bf) {
  int bid = blockIdx.x;
  if (bid < 16384) {
    int i = bid * 256 + threadIdx.x;
    float4 f = f4[i];
    float4 e = e4[i];
    union { unsigned short u[4]; uint2 v; } pz;
    pz.u[0] = f2bf(f.x + e.x);
    pz.u[1] = f2bf(f.y + e.y);
    pz.u[2] = f2bf(f.z + e.z);
    pz.u[3] = f2bf(f.w + e.w);
    z[i] = pz.v;
  } else {
    int j = ((bid - 16384) * 256 + threadIdx.x) * 8;   // elem idx in [1024][2048]
    int row = j >> 11;
    int col = j & 2047;
    union { unsigned short u[8]; uint4 v; } pk;
    if (row < C_DIM) {
      const float* src = cls_w + (size_t)row * D_DIM + col;
#pragma unroll
      for (int i2 = 0; i2 < 8; ++i2) pk.u[i2] = f2bf(src[i2]);
    } else {
#pragma unroll
      for (int i2 = 0; i2 < 8; ++i2) pk.u[i2] = 0;
    }
    *(uint4*)((unsigned short*)clsw_bf + j) = pk.v;
  }
}

// ---- C: probs_raw = z @ cls_w^T + cls_b   (r13 proven: fastest gemm variant)
// BM=128, BN=64, BK=64, single-buffer. Grid (64,16)=1024 blocks (4/CU).
// 4 waves as 2x2, each 64x32 output (acc[4][2]). LDS 24KB, XOR-swizzled:
// 16B chunk (row, cc) at slot row*8 + (cc ^ (row&7)).
__global__ __launch_bounds__(256) void gemm_bt(const __hip_bfloat16* __restrict__ A,
                                               const __hip_bfloat16* __restrict__ Bt,
                                               const float* __restrict__ cls_b,
                                               float* __restrict__ out) {
  __shared__ __align__(16) __hip_bfloat16 sA[128 * 64];   // 16 KB
  __shared__ __align__(16) __hip_bfloat16 sB[64 * 64];    //  8 KB
  const int tid = threadIdx.x;
  const int m0 = blockIdx.x * 128;
  const int n0 = blockIdx.y * 64;
  const int w = tid >> 6, lane = tid & 63;
  const int wm = (w & 1) * 64, wn = (w >> 1) * 32;
  const int l15 = lane & 15, quad = lane >> 4;

  f32x4 acc[4][2] = {};

  for (int k0 = 0; k0 < D_DIM; k0 += 64) {
#pragma unroll
    for (int i = 0; i < 4; ++i) {
      int j = i * 256 + tid;          // A: 1024 chunks of 16B (128 rows x 8)
      int row = j >> 3;
      int cc = (j & 7) ^ (row & 7);   // inverse of the swizzle (XOR involution)
      GLOAD_LDS16(A + (size_t)(m0 + row) * D_DIM + k0 + cc * 8, &sA[j * 8]);
    }
#pragma unroll
    for (int i = 0; i < 2; ++i) {
      int j = i * 256 + tid;          // B: 512 chunks (64 rows x 8)
      int row = j >> 3;
      int cc = (j & 7) ^ (row & 7);
      GLOAD_LDS16(Bt + (size_t)(n0 + row) * D_DIM + k0 + cc * 8, &sB[j * 8]);
    }
    __syncthreads();
#pragma unroll
    for (int kk = 0; kk < 64; kk += 32) {
      const int ccr = (kk >> 3) + quad;   // which 8-elem chunk along K
      short8 af[4], bfr[2];
#pragma unroll
      for (int i = 0; i < 4; ++i) {
        int r = wm + i * 16 + l15;
        af[i] = *(const short8*)&sA[(r * 8 + (ccr ^ (r & 7))) * 8];
      }
#pragma unroll
      for (int jn = 0; jn < 2; ++jn) {
        int r = wn + jn * 16 + l15;
        bfr[jn] = *(const short8*)&sB[(r * 8 + (ccr ^ (r & 7))) * 8];
      }
#pragma unroll
      for (int i = 0; i < 4; ++i)
#pragma unroll
        for (int jn = 0; jn < 2; ++jn)
          acc[i][jn] = __builtin_amdgcn_mfma_f32_16x16x32_bf16(af[i], bfr[jn], acc[i][jn], 0, 0, 0);
    }
    __syncthreads();
  }

  // epilogue: C/D layout col=lane&15, row=quad*4+reg  (m89-verified)
#pragma unroll
  for (int i = 0; i < 4; ++i) {
    int row = m0 + wm + i * 16 + quad * 4;
#pragma unroll
    for (int jn = 0; jn < 2; ++jn) {
      int col = n0 + wn + jn * 16 + l15;
      if (col < C_DIM) {
        float bias = cls_b[col];
#pragma unroll
        for (int r = 0; r < 4; ++r)
          out[(size_t)(row + r) * C_DIM + col] = acc[i][jn][r] + bias;
      }
    }
  }
}

// ---- D: per-row normalize+clamp+log, 4 rows per wave (round 12, proven).
// All 16 float4 loads issued before use (ILP-16); 4 independent reduce chains.
// Grid 512 blocks x 4 waves x 4 rows = 8192 rows.
__global__ __launch_bounds__(256) void rownorm(float* __restrict__ out,
                                               const int* __restrict__ target,
                                               float* __restrict__ rowloss) {
  const int wv = threadIdx.x >> 6, lane = threadIdx.x & 63;
  const int r0 = blockIdx.x * 16 + wv * 4;

  float v[4][16];
#pragma unroll
  for (int rr = 0; rr < 4; ++rr) {
    const float* row = out + (size_t)(r0 + rr) * C_DIM;
#pragma unroll
    for (int k = 0; k < 4; ++k) {
      int c = k * 256 + lane * 4;
      if (c + 3 < C_DIM) {
        float4 f = *(const float4*)(row + c);
        v[rr][k * 4 + 0] = f.x; v[rr][k * 4 + 1] = f.y;
        v[rr][k * 4 + 2] = f.z; v[rr][k * 4 + 3] = f.w;
      } else {
#pragma unroll
        for (int i = 0; i < 4; ++i) v[rr][k * 4 + i] = (c + i < C_DIM) ? row[c + i] : 0.f;
      }
    }
  }

  float s[4];
#pragma unroll
  for (int rr = 0; rr < 4; ++rr) {
    float a = 0.f;
#pragma unroll
    for (int k = 0; k < 16; ++k) a += v[rr][k];
    s[rr] = a;
  }
#pragma unroll
  for (int rr = 0; rr < 4; ++rr) {
#pragma unroll
    for (int off = 32; off > 0; off >>= 1) s[rr] += __shfl_down(s[rr], off, 64);
    s[rr] = __shfl(s[rr], 0, 64);
  }

  int tg[4];
#pragma unroll
  for (int rr = 0; rr < 4; ++rr) tg[rr] = target[r0 + rr];

#pragma unroll
  for (int rr = 0; rr < 4; ++rr) {
    float inv = 1.0f / s[rr];
    float* row = out + (size_t)(r0 + rr) * C_DIM;
#pragma unroll
    for (int k = 0; k < 4; ++k) {
      int c = k * 256 + lane * 4;
      float lg[4];
#pragma unroll
      for (int i = 0; i < 4; ++i) {
        float p = v[rr][k * 4 + i] * inv;
        p = fminf(fmaxf(p, EPS32), 1.0f - EPS32);
        lg[i] = __logf(p);
        if (c + i == tg[rr]) rowloss[r0 + rr] = -lg[i];
      }
      if (c + 3 < C_DIM) {
        *(float4*)(row + c) = make_float4(lg[0], lg[1], lg[2], lg[3]);
      } else {
#pragma unroll
        for (int i = 0; i < 4; ++i) if (c + i < C_DIM) row[c + i] = lg[i];
      }
    }
  }
}

// ---- E: loss = mean(rowloss). One 1024-thread block, ILP-8, plain store.
__global__ __launch_bounds__(1024) void finalize(const float* __restrict__ rowloss,
                                                 float* __restrict__ out_loss) {
  int tid = threadIdx.x;
  float a[8];
#pragma unroll
  for (int j = 0; j < 8; ++j) a[j] = rowloss[tid + j * 1024];
  float s = 0.f;
#pragma unroll
  for (int j = 0; j < 8; ++j) s += a[j];
  s = wave_red(s);
  __shared__ float sm[16];
  if ((tid & 63) == 0) sm[tid >> 6] = s;
  __syncthreads();
  if (tid == 0) {
    float t = 0.f;
#pragma unroll
    for (int k = 0; k < 16; ++k) t += sm[k];
    out_loss[0] = t * (1.0f / B_ROWS);
  }
}

extern "C" void kernel_launch(void* const* d_in, const int* in_sizes, int n_in,
                              void* d_out, int out_size, void* d_ws, size_t ws_size,
                              hipStream_t stream) {
  const float* feature = (const float*)d_in[0];
  const float* cls_w   = (const float*)d_in[3];
  const float* cls_b   = (const float*)d_in[4];
  const float* eps     = (const float*)d_in[5];
  const int*   target  = (const int*)d_in[6];
  float* out = (float*)d_out;
  float* out_loss = out + (size_t)B_ROWS * C_DIM;

  char* ws = (char*)d_ws;
  __hip_bfloat16* z_bf    = (__hip_bfloat16*)ws;                // 33554432 B
  __hip_bfloat16* clsw_bf = (__hip_bfloat16*)(ws + 33554432);   //  4194304 B
  float*          rowloss = (float*)(ws + 33554432 + 4194304);  //    32768 B

  fuse_z<<<dim3(16384 + 1024), 256, 0, stream>>>((const float4*)feature, (const float4*)eps,
                                                 (uint2*)z_bf, cls_w, clsw_bf);
  gemm_bt<<<dim3(B_ROWS / 128, C_PAD / 64), 256, 0, stream>>>(z_bf, clsw_bf, cls_b, out);
  rownorm<<<dim3(B_ROWS / 16), 256, 0, stream>>>(out, target, rowloss);
  finalize<<<dim3(1), 1024, 0, stream>>>(rowloss, out_loss);
}